// Round 3
// baseline (183.164 us; speedup 1.0000x reference)
//
#include <hip/hip_runtime.h>
#include <hip/hip_bf16.h>
#include <stdint.h>

#define HH 8
#define DD 128
#define MAXSEQ 2048
#define QBLK 128
#define KVB 32

typedef float f32x16 __attribute__((ext_vector_type(16)));
typedef short s16x8 __attribute__((ext_vector_type(8)));

__device__ __forceinline__ unsigned short f2bf(float x) {
  union { float f; uint32_t u; } v; v.f = x;
  uint32_t u = v.u;
  return (unsigned short)((u + 0x7FFFu + ((u >> 16) & 1u)) >> 16);
}

__device__ __forceinline__ void gload_lds16(const unsigned short* g, unsigned short* l) {
  __builtin_amdgcn_global_load_lds((const __attribute__((address_space(1))) void*)g,
                                   (__attribute__((address_space(3))) void*)l, 16, 0, 0);
}

// ---- prepass 0: zero rows not covered by any sequence ----
__global__ void zero_rows(const int* __restrict__ cuq, float* __restrict__ out, int T, int B) {
  const int t = blockIdx.x * blockDim.x + threadIdx.x;
  if (t >= T) return;
  bool covered = false;
  for (int b = 0; b < B; ++b) {
    const int s = cuq[b];
    const int len = min(cuq[b + 1] - s, MAXSEQ);
    if (t >= s && t < s + len) covered = true;
  }
  if (!covered) {
    float4* p = (float4*)(out + (size_t)t * HH * DD);
#pragma unroll 4
    for (int i = 0; i < HH * DD / 4; ++i) p[i] = float4{0.f, 0.f, 0.f, 0.f};
  }
}

// ---- prepass 1: K [T,H,D] f32 -> Kb [H,T,D] bf16 ----
__global__ void kconv(const float* __restrict__ k, unsigned short* __restrict__ kb, int T) {
  long i = (long)blockIdx.x * blockDim.x + threadIdx.x;
  long total = (long)T * HH * DD / 4;
  if (i >= total) return;
  long e = i * 4;
  int d = (int)(e % DD);
  int h = (int)((e / DD) % HH);
  long t = e / (DD * HH);
  float4 a = *(const float4*)(k + e);
  ushort4 o;
  o.x = f2bf(a.x); o.y = f2bf(a.y); o.z = f2bf(a.z); o.w = f2bf(a.w);
  *(ushort4*)(kb + ((size_t)h * T + (size_t)t) * DD + d) = o;
}

// ---- prepass 2: V [T,H,D] f32 -> Vt [H,D,T] bf16 (transpose) ----
__global__ void vtrans(const float* __restrict__ v, unsigned short* __restrict__ vt, int T) {
  __shared__ float tile[64][65];
  const int t0 = blockIdx.x * 64;
  const int d0 = blockIdx.y * 64;
  const int h = blockIdx.z;
  const int tid = threadIdx.x;
  const int row = tid >> 2;
  const int c0 = (tid & 3) * 16;
  const int tr = min(t0 + row, T - 1);
  const float* src = v + ((size_t)tr * HH + h) * DD + d0 + c0;
#pragma unroll
  for (int cc = 0; cc < 16; cc += 4) {
    float4 x = *(const float4*)(src + cc);
    tile[row][c0 + cc + 0] = x.x;
    tile[row][c0 + cc + 1] = x.y;
    tile[row][c0 + cc + 2] = x.z;
    tile[row][c0 + cc + 3] = x.w;
  }
  __syncthreads();
  unsigned short* dst = vt + ((size_t)h * DD + d0 + row) * (size_t)T + t0 + c0;
#pragma unroll
  for (int cc = 0; cc < 16; cc += 4) {
    if (t0 + c0 + cc + 3 < T) {
      ushort4 o;
      o.x = f2bf(tile[c0 + cc + 0][row]);
      o.y = f2bf(tile[c0 + cc + 1][row]);
      o.z = f2bf(tile[c0 + cc + 2][row]);
      o.w = f2bf(tile[c0 + cc + 3][row]);
      *(ushort4*)(dst + cc) = o;
    }
  }
}

// ---- main: 8-wave (4 q-strips x 2 kv-halves) flash attention, KVB=32, in-LDS merge ----
// LDS: 4 slots of 16KB: slot(wk,buf) = (wk*2+buf)*8192 ushorts; K at +0 (32x128), V at +4096.
// V layout per slot: row r (0..63, 128B) holds d=2r,2r+1 x 32 keys, chunk-XOR swizzled:
//   16B chunk (r, ph): ph = tt ^ (r&7), tt = (d&1)*4 + kq (kq = key/8)
__global__ __launch_bounds__(512, 4)
void attn_main(const float* __restrict__ q,
               const unsigned short* __restrict__ kb,
               const unsigned short* __restrict__ vt,
               const int* __restrict__ cuq,
               const int* __restrict__ cuk,
               float* __restrict__ out,
               int T, int BH) {
  extern __shared__ __align__(16) unsigned short smem[];

  const int bid = blockIdx.x;
  const int bh = bid % BH;
  const int qt = bid / BH;
  const int b = bh / HH, h = bh % HH;
  const int qs = cuq[b], qe = cuq[b + 1];
  const int ks = cuk[b], ke = cuk[b + 1];
  const int nq = min(qe - qs, MAXSEQ);
  const int nk = min(ke - ks, MAXSEQ);
  if (qt * QBLK >= nq || nk <= 0) return;

  const int tid = threadIdx.x;
  const int wave = tid >> 6;
  const int lane = tid & 63;
  const int lo = lane & 31;
  const int hi = lane >> 5;
  const int wq = wave & 3;
  const int wk = wave >> 2;

  const unsigned short* kbh = kb + (size_t)h * T * DD;
  const unsigned short* vth = vt + (size_t)h * DD * (size_t)T;

  // ---- Q fragments (B-operand of S^T = K * Q^T); fold 1/sqrt(D)*log2(e) ----
  const float SC = (1.0f / 11.313708498984761f) * 1.4426950408889634f;
  const int qrow = qt * QBLK + wq * 32 + lo;
  const int qg = qs + min(qrow, nq - 1);
  const float* qp = q + ((size_t)qg * HH + h) * DD;
  s16x8 qf[8];
#pragma unroll
  for (int s = 0; s < 8; ++s) {
    const float* p0 = qp + s * 16 + hi * 8;
    float4 a = *(const float4*)(p0);
    float4 c = *(const float4*)(p0 + 4);
    union { unsigned short us[8]; s16x8 v; } u;
    u.us[0] = f2bf(a.x * SC); u.us[1] = f2bf(a.y * SC);
    u.us[2] = f2bf(a.z * SC); u.us[3] = f2bf(a.w * SC);
    u.us[4] = f2bf(c.x * SC); u.us[5] = f2bf(c.y * SC);
    u.us[6] = f2bf(c.z * SC); u.us[7] = f2bf(c.w * SC);
    qf[s] = u.v;
  }

  f32x16 Oa[4];
#pragma unroll
  for (int i = 0; i < 4; ++i)
#pragma unroll
    for (int r = 0; r < 16; ++r) Oa[i][r] = 0.0f;

  float m_run = -__builtin_inff();
  float l_run = 0.0f;

  // this wave's kv-half
  const int len_wk = min(nk - wk * 1024, 1024);              // may be <=0
  const int myT = len_wk > 0 ? (len_wk + KVB - 1) / KVB : 0; // tiles this wave computes
  const int nkt = (min(nk, 1024) + KVB - 1) / KVB;           // block-uniform loop count (half0 >= half1)

  // ---- staging: both halves' tiles, pre-swizzled source -> linear LDS dest ----
  auto stage = [&](int buf, int kt) {
#pragma unroll
    for (int wkk = 0; wkk < 2; ++wkk) {
      unsigned short* slot = smem + (size_t)(wkk * 2 + buf) * 8192;
      const int kb0 = ks + wkk * 1024 + kt * KVB;
      {
        const int key = tid >> 4, seg = tid & 15;
        const int col = (seg * 8) ^ ((key & 7) << 3);
        const int gk = min(kb0 + key, T - 1);
        gload_lds16(kbh + (size_t)gk * DD + col, slot + (size_t)(tid & ~63) * 8);
      }
      {
        const int r = tid >> 3, ph = tid & 7;
        const int tt = ph ^ (r & 7);
        const int d = 2 * r + (tt >> 2);
        const int tc = min(kb0 + (tt & 3) * 8, T - 8);
        gload_lds16(vth + (size_t)d * T + tc, slot + 4096 + (size_t)(tid & ~63) * 8);
      }
    }
  };

  stage(0, 0);
  __syncthreads();

  int cur = 0;
  for (int kt = 0; kt < nkt; ++kt) {
    if (kt + 1 < nkt) stage(cur ^ 1, kt + 1);

    if (kt < myT) {
      const unsigned short* Kl = smem + (size_t)(wk * 2 + cur) * 8192;
      const unsigned short* Vl = Kl + 4096;

      // ---- S^T = K * Q^T (one 32x32 tile, 32 keys) ----
      f32x16 st;
#pragma unroll
      for (int r = 0; r < 16; ++r) st[r] = 0.0f;
      __builtin_amdgcn_s_setprio(1);
#pragma unroll
      for (int s = 0; s < 8; ++s) {
        const int idx = (lo * DD + s * 16 + hi * 8) ^ ((lo & 7) << 3);
        s16x8 kf = *(const s16x8*)(&Kl[idx]);
        st = __builtin_amdgcn_mfma_f32_32x32x16_bf16(kf, qf[s], st, 0, 0, 0);
      }
      __builtin_amdgcn_s_setprio(0);

      // mask keys beyond this half's length (last partial tile only)
      const int lim = len_wk - kt * KVB;
      if (lim < KVB) {
#pragma unroll
        for (int r = 0; r < 16; ++r) {
          const int base = (r & 3) + 8 * (r >> 2) + 4 * hi;
          if (base >= lim) st[r] = -__builtin_inff();
        }
      }

      // ---- online softmax with defer-max (THR=8 in log2 domain) ----
      float tmax = -__builtin_inff();
#pragma unroll
      for (int r = 0; r < 16; ++r) tmax = fmaxf(tmax, st[r]);
      tmax = fmaxf(tmax, __shfl_xor(tmax, 32));

      if (!__all(tmax <= m_run + 8.0f)) {
        const float m_new = fmaxf(m_run, tmax);
        const float alpha = __builtin_amdgcn_exp2f(m_run - m_new);
        l_run *= alpha;
        m_run = m_new;
#pragma unroll
        for (int r = 0; r < 16; ++r) {
          const int src = (r & 3) + 8 * (r >> 2) + 4 * hi;
          const float af = __shfl(alpha, src);
          Oa[0][r] *= af; Oa[1][r] *= af; Oa[2][r] *= af; Oa[3][r] *= af;
        }
      }

      float p[16];
      float psum = 0.0f;
#pragma unroll
      for (int r = 0; r < 16; ++r) {
        p[r] = __builtin_amdgcn_exp2f(st[r] - m_run);
        psum += p[r];
      }
      psum += __shfl_xor(psum, 32);
      l_run += psum;

      // ---- pack P to bf16 (cvt_pk); chunk c: keys 8c+4hi+e -> p[4c+e] ----
      uint32_t ownu[8];
#pragma unroll
      for (int c = 0; c < 4; ++c) {
        uint32_t w0, w1;
        asm("v_cvt_pk_bf16_f32 %0, %1, %2" : "=v"(w0) : "v"(p[4 * c + 0]), "v"(p[4 * c + 1]));
        asm("v_cvt_pk_bf16_f32 %0, %1, %2" : "=v"(w1) : "v"(p[4 * c + 2]), "v"(p[4 * c + 3]));
        ownu[c * 2 + 0] = w0;
        ownu[c * 2 + 1] = w1;
      }

      // ---- O += P * V (2 key-slots x 4 d-tiles) ----
      __builtin_amdgcn_s_setprio(1);
#pragma unroll
      for (int ks2 = 0; ks2 < 2; ++ks2) {
        uint32_t a0 = ownu[4 * ks2 + 0], b0 = ownu[4 * ks2 + 2];
        uint32_t a1 = ownu[4 * ks2 + 1], b1 = ownu[4 * ks2 + 3];
        asm("v_permlane32_swap_b32 %0, %1" : "+v"(a0), "+v"(b0));
        asm("v_permlane32_swap_b32 %0, %1" : "+v"(a1), "+v"(b1));
        union { uint32_t u[4]; s16x8 v; } pu;
        pu.u[0] = a0; pu.u[1] = a1; pu.u[2] = b0; pu.u[3] = b1;
#pragma unroll
        for (int dt = 0; dt < 4; ++dt) {
          const int r = dt * 16 + (lo >> 1);
          const int ph = ((lo & 1) * 4 + ks2 * 2 + hi) ^ ((lo >> 1) & 7);
          const int idx = r * 64 + ph * 8;
          s16x8 vf = *(const s16x8*)(&Vl[idx]);
          Oa[dt] = __builtin_amdgcn_mfma_f32_32x32x16_bf16(pu.v, vf, Oa[dt], 0, 0, 0);
        }
      }
      __builtin_amdgcn_s_setprio(0);
    }

    if (kt + 1 < nkt) {
      __syncthreads();
      cur ^= 1;
    }
  }

  // ---- merge the two kv-halves through LDS ----
  float* fsm = (float*)smem;
  __syncthreads();
  if (hi == 0) {
    fsm[wk * 256 + wq * 64 + lo] = m_run;
    fsm[wk * 256 + wq * 64 + 32 + lo] = l_run;
  }
  __syncthreads();
  const int po = (wk ^ 1) * 256 + wq * 64 + lo;
  const float m_o = fsm[po];
  const float l_o = fsm[po + 32];
  const float mstar = fmaxf(m_run, m_o);
  const float a_own = (l_run == 0.f) ? 0.f : __builtin_amdgcn_exp2f(m_run - mstar);
  const float a_oth = (l_o == 0.f) ? 0.f : __builtin_amdgcn_exp2f(m_o - mstar);
  __syncthreads();  // everyone done reading m/l before Obuf overwrites that region

  if (wk == 1) {
    // write a_own-scaled Oa to Obuf[wq][q][d]
#pragma unroll
    for (int r = 0; r < 16; ++r) {
      const int src = (r & 3) + 8 * (r >> 2) + 4 * hi;
      const float af = __shfl(a_own, src);
      float* row = fsm + (size_t)wq * 4096 + (size_t)src * 128;
      row[0 * 32 + lo] = Oa[0][r] * af;
      row[1 * 32 + lo] = Oa[1][r] * af;
      row[2 * 32 + lo] = Oa[2][r] * af;
      row[3 * 32 + lo] = Oa[3][r] * af;
    }
  }
  __syncthreads();
  if (wk == 0) {
    const float lst = a_own * l_run + a_oth * l_o;
    const float linv = 1.0f / lst;
#pragma unroll
    for (int r = 0; r < 16; ++r) {
      const int src = (r & 3) + 8 * (r >> 2) + 4 * hi;
      const float af = __shfl(a_own, src);
      const float li = __shfl(linv, src);
      const int qirow = qt * QBLK + wq * 32 + src;
      if (qirow < nq) {
        const float* row = fsm + (size_t)wq * 4096 + (size_t)src * 128;
        float* op = out + ((size_t)(qs + qirow) * HH + h) * DD;
        op[0 * 32 + lo] = (Oa[0][r] * af + row[0 * 32 + lo]) * li;
        op[1 * 32 + lo] = (Oa[1][r] * af + row[1 * 32 + lo]) * li;
        op[2 * 32 + lo] = (Oa[2][r] * af + row[2 * 32 + lo]) * li;
        op[3 * 32 + lo] = (Oa[3][r] * af + row[3 * 32 + lo]) * li;
      }
    }
  }
}

extern "C" void kernel_launch(void* const* d_in, const int* in_sizes, int n_in,
                              void* d_out, int out_size, void* d_ws, size_t ws_size,
                              hipStream_t stream) {
  const float* q = (const float*)d_in[0];
  const float* k = (const float*)d_in[1];
  const float* v = (const float*)d_in[2];
  const int* cuq = (const int*)d_in[3];
  const int* cuk = (const int*)d_in[4];
  float* out = (float*)d_out;
  const int T = in_sizes[0] / (HH * DD);
  const int B = in_sizes[3] - 1;

  unsigned short* kb = (unsigned short*)d_ws;
  unsigned short* vt = kb + (size_t)T * HH * DD;
  const size_t need = (size_t)T * HH * DD * 2 * 2;
  if (ws_size < need) return;

  {
    zero_rows<<<(T + 255) / 256, 256, 0, stream>>>(cuq, out, T, B);
  }
  {
    long total4 = (long)T * HH * DD / 4;
    int blocks = (int)((total4 + 255) / 256);
    kconv<<<blocks, 256, 0, stream>>>(k, kb, T);
  }
  {
    dim3 g((unsigned)((T + 63) / 64), DD / 64, HH);
    vtrans<<<g, 256, 0, stream>>>(v, vt, T);
  }
  {
    const int BH = B * HH;
    const int scap = MAXSEQ < T ? MAXSEQ : T;
    const int qtiles = (scap + QBLK - 1) / QBLK;
    attn_main<<<BH * qtiles, 512, 65536, stream>>>(q, kb, vt, cuq, cuk, out, T, BH);
  }
}

// Round 4
// 114.052 us; speedup vs baseline: 1.6060x; 1.6060x over previous
//
#include <hip/hip_runtime.h>
#include <hip/hip_bf16.h>
#include <stdint.h>

#define HH 8
#define DD 128
#define MAXSEQ 2048
#define QBLK 128
#define KVB 64

typedef float f32x16 __attribute__((ext_vector_type(16)));
typedef short s16x8 __attribute__((ext_vector_type(8)));

__device__ __forceinline__ unsigned short f2bf(float x) {
  union { float f; uint32_t u; } v; v.f = x;
  uint32_t u = v.u;
  return (unsigned short)((u + 0x7FFFu + ((u >> 16) & 1u)) >> 16);
}

__device__ __forceinline__ void gload_lds16(const unsigned short* g, unsigned short* l) {
  __builtin_amdgcn_global_load_lds((const __attribute__((address_space(1))) void*)g,
                                   (__attribute__((address_space(3))) void*)l, 16, 0, 0);
}

// ---- prepass 0: zero rows not covered by any sequence ----
__global__ void zero_rows(const int* __restrict__ cuq, float* __restrict__ out, int T, int B) {
  const int t = blockIdx.x * blockDim.x + threadIdx.x;
  if (t >= T) return;
  bool covered = false;
  for (int b = 0; b < B; ++b) {
    const int s = cuq[b];
    const int len = min(cuq[b + 1] - s, MAXSEQ);
    if (t >= s && t < s + len) covered = true;
  }
  if (!covered) {
    float4* p = (float4*)(out + (size_t)t * HH * DD);
#pragma unroll 4
    for (int i = 0; i < HH * DD / 4; ++i) p[i] = float4{0.f, 0.f, 0.f, 0.f};
  }
}

// ---- prepass 1: K [T,H,D] f32 -> Kb [H,T,D] bf16 ----
__global__ void kconv(const float* __restrict__ k, unsigned short* __restrict__ kb, int T) {
  long i = (long)blockIdx.x * blockDim.x + threadIdx.x;
  long total = (long)T * HH * DD / 4;
  if (i >= total) return;
  long e = i * 4;
  int d = (int)(e % DD);
  int h = (int)((e / DD) % HH);
  long t = e / (DD * HH);
  float4 a = *(const float4*)(k + e);
  ushort4 o;
  o.x = f2bf(a.x); o.y = f2bf(a.y); o.z = f2bf(a.z); o.w = f2bf(a.w);
  *(ushort4*)(kb + ((size_t)h * T + (size_t)t) * DD + d) = o;
}

// ---- prepass 2: V [T,H,D] f32 -> Vt [H,D,T] bf16 (transpose) ----
__global__ void vtrans(const float* __restrict__ v, unsigned short* __restrict__ vt, int T) {
  __shared__ float tile[64][65];
  const int t0 = blockIdx.x * 64;
  const int d0 = blockIdx.y * 64;
  const int h = blockIdx.z;
  const int tid = threadIdx.x;
  const int row = tid >> 2;
  const int c0 = (tid & 3) * 16;
  const int tr = min(t0 + row, T - 1);
  const float* src = v + ((size_t)tr * HH + h) * DD + d0 + c0;
#pragma unroll
  for (int cc = 0; cc < 16; cc += 4) {
    float4 x = *(const float4*)(src + cc);
    tile[row][c0 + cc + 0] = x.x;
    tile[row][c0 + cc + 1] = x.y;
    tile[row][c0 + cc + 2] = x.z;
    tile[row][c0 + cc + 3] = x.w;
  }
  __syncthreads();
  unsigned short* dst = vt + ((size_t)h * DD + d0 + row) * (size_t)T + t0 + c0;
#pragma unroll
  for (int cc = 0; cc < 16; cc += 4) {
    if (t0 + c0 + cc + 3 < T) {
      ushort4 o;
      o.x = f2bf(tile[c0 + cc + 0][row]);
      o.y = f2bf(tile[c0 + cc + 1][row]);
      o.z = f2bf(tile[c0 + cc + 2][row]);
      o.w = f2bf(tile[c0 + cc + 3][row]);
      *(ushort4*)(dst + cc) = o;
    }
  }
}

// ---- main: 4-wave swapped-QK^T flash attention, dbuf LDS + global_load_lds ----
// Phase-structured inner loop: batched K-frag reads -> stage(t+1) -> QK MFMA ->
// V-frag batch A -> softmax/pack (hides V latency) -> V batch B + PV MFMAs.
__global__ __launch_bounds__(256, 2)
void attn_main(const float* __restrict__ q,
               const unsigned short* __restrict__ kb,
               const unsigned short* __restrict__ vt,
               const int* __restrict__ cuq,
               const int* __restrict__ cuk,
               float* __restrict__ out,
               int T, int BH) {
  extern __shared__ __align__(16) unsigned short smem[];
  // layout (ushort elems): K buf b at b*8192 (64x128); V buf b at 16384 + b*8192 (128x64)

  const int bid = blockIdx.x;
  const int bh = bid % BH;
  const int qt = bid / BH;
  const int b = bh / HH, h = bh % HH;
  const int qs = cuq[b], qe = cuq[b + 1];
  const int ks = cuk[b], ke = cuk[b + 1];
  const int nq = min(qe - qs, MAXSEQ);
  const int nk = min(ke - ks, MAXSEQ);
  if (qt * QBLK >= nq || nk <= 0) return;

  const int tid = threadIdx.x;
  const int wave = tid >> 6;
  const int lane = tid & 63;
  const int lo = lane & 31;
  const int hi = lane >> 5;
  const int wbase8 = (tid & ~63) * 8;  // wave-uniform LDS elem base for staging

  const unsigned short* kbh = kb + (size_t)h * T * DD;
  const unsigned short* vth = vt + (size_t)h * DD * (size_t)T;

  // ---- Q fragments (B-operand of S^T = K * Q^T); fold 1/sqrt(D)*log2(e) ----
  const float SC = (1.0f / 11.313708498984761f) * 1.4426950408889634f;
  const int qrow = qt * QBLK + wave * 32 + lo;
  const int qg = qs + min(qrow, nq - 1);
  const float* qp = q + ((size_t)qg * HH + h) * DD;
  s16x8 qf[8];
#pragma unroll
  for (int s = 0; s < 8; ++s) {
    const float* p0 = qp + s * 16 + hi * 8;
    float4 a = *(const float4*)(p0);
    float4 c = *(const float4*)(p0 + 4);
    union { unsigned short us[8]; s16x8 v; } u;
    u.us[0] = f2bf(a.x * SC); u.us[1] = f2bf(a.y * SC);
    u.us[2] = f2bf(a.z * SC); u.us[3] = f2bf(a.w * SC);
    u.us[4] = f2bf(c.x * SC); u.us[5] = f2bf(c.y * SC);
    u.us[6] = f2bf(c.z * SC); u.us[7] = f2bf(c.w * SC);
    qf[s] = u.v;
  }

  f32x16 Oa[4];
#pragma unroll
  for (int i = 0; i < 4; ++i)
#pragma unroll
    for (int r = 0; r < 16; ++r) Oa[i][r] = 0.0f;

  float m_run = -__builtin_inff();
  float l_run = 0.0f;

  const int nkt = (nk + KVB - 1) / KVB;

  // ---- staging: pre-swizzled global source -> linear LDS (global_load_lds) ----
  auto stage = [&](int buf, int kt) {
    const int k0 = ks + kt * KVB;
    unsigned short* Kd = smem + buf * 8192;
    unsigned short* Vd = smem + 16384 + buf * 8192;
#pragma unroll
    for (int r = 0; r < 4; ++r) {
      const int g = r * 256 + tid;
      const int key = g >> 4, seg = g & 15;
      const int col = (seg * 8) ^ ((key & 7) << 3);
      const int gk = min(k0 + key, T - 1);
      gload_lds16(kbh + (size_t)gk * DD + col, Kd + (size_t)(r * 256) * 8 + wbase8);
    }
#pragma unroll
    for (int r = 0; r < 4; ++r) {
      const int g = r * 256 + tid;
      const int dr = g >> 3, sg = g & 7;
      const int colk = (sg * 8) ^ ((dr & 7) << 3);
      const int tc = min(k0 + colk, T - 8);
      gload_lds16(vth + (size_t)dr * T + tc, Vd + (size_t)(r * 256) * 8 + wbase8);
    }
  };

  stage(0, 0);
  __syncthreads();

  int cur = 0;
  for (int kt = 0; kt < nkt; ++kt) {
    const unsigned short* Kb = smem + cur * 8192;
    const unsigned short* Vb = smem + 16384 + cur * 8192;

    // ---- Phase 1: batch all 16 K-fragment reads (pipelined in LDS queue) ----
    s16x8 kf[16];
#pragma unroll
    for (int s = 0; s < 8; ++s) {
      const int i0 = (lo * DD + s * 16 + hi * 8) ^ ((lo & 7) << 3);
      const int i1 = ((32 + lo) * DD + s * 16 + hi * 8) ^ ((lo & 7) << 3);
      kf[2 * s] = *(const s16x8*)(&Kb[i0]);
      kf[2 * s + 1] = *(const s16x8*)(&Kb[i1]);
    }

    // ---- Phase 1b: issue next tile's staging (VALU+VMEM fills the lgkm wait) ----
    if (kt + 1 < nkt) stage(cur ^ 1, kt + 1);

    // ---- Phase 2: S^T = K * Q^T ----
    f32x16 st0, st1;
#pragma unroll
    for (int r = 0; r < 16; ++r) { st0[r] = 0.0f; st1[r] = 0.0f; }
    __builtin_amdgcn_s_setprio(1);
#pragma unroll
    for (int s = 0; s < 8; ++s) {
      st0 = __builtin_amdgcn_mfma_f32_32x32x16_bf16(kf[2 * s], qf[s], st0, 0, 0, 0);
      st1 = __builtin_amdgcn_mfma_f32_32x32x16_bf16(kf[2 * s + 1], qf[s], st1, 0, 0, 0);
    }
    __builtin_amdgcn_s_setprio(0);

    // ---- Phase 3: V-fragment batch A (ks2=0,1) — latency hidden under softmax ----
    s16x8 vfA[8];
#pragma unroll
    for (int ks2 = 0; ks2 < 2; ++ks2)
#pragma unroll
      for (int dt = 0; dt < 4; ++dt) {
        const int d = dt * 32 + lo;
        const int idx = (d * KVB + ks2 * 16 + hi * 8) ^ ((d & 7) << 3);
        vfA[ks2 * 4 + dt] = *(const s16x8*)(&Vb[idx]);
      }

    // ---- Phase 4: mask + online softmax (defer-max THR=8, log2 domain) ----
    if (kt * KVB + KVB > nk) {
#pragma unroll
      for (int r = 0; r < 16; ++r) {
        const int base = (r & 3) + 8 * (r >> 2) + 4 * hi;
        if (kt * KVB + base >= nk) st0[r] = -__builtin_inff();
        if (kt * KVB + 32 + base >= nk) st1[r] = -__builtin_inff();
      }
    }

    float tmax = -__builtin_inff();
#pragma unroll
    for (int r = 0; r < 16; ++r) tmax = fmaxf(tmax, fmaxf(st0[r], st1[r]));
    tmax = fmaxf(tmax, __shfl_xor(tmax, 32));

    if (!__all(tmax <= m_run + 8.0f)) {
      const float m_new = fmaxf(m_run, tmax);
      const float alpha = __builtin_amdgcn_exp2f(m_run - m_new);
      l_run *= alpha;
      m_run = m_new;
#pragma unroll
      for (int r = 0; r < 16; ++r) {
        const int src = (r & 3) + 8 * (r >> 2) + 4 * hi;
        const float af = __shfl(alpha, src);
        Oa[0][r] *= af; Oa[1][r] *= af; Oa[2][r] *= af; Oa[3][r] *= af;
      }
    }

    float p[32];
    float psum = 0.0f;
#pragma unroll
    for (int r = 0; r < 16; ++r) {
      p[r] = __builtin_amdgcn_exp2f(st0[r] - m_run);
      p[16 + r] = __builtin_amdgcn_exp2f(st1[r] - m_run);
      psum += p[r] + p[16 + r];
    }
    psum += __shfl_xor(psum, 32);
    l_run += psum;

    // pack P to bf16 (cvt_pk); chunk c (0..7): keys 8c+4hi+e -> p[(c>>2)*16 + 4*(c&3) + e]
    uint32_t ownu[16];
#pragma unroll
    for (int c = 0; c < 8; ++c) {
      const int t = c >> 2, rb = 4 * (c & 3);
      uint32_t w0, w1;
      asm("v_cvt_pk_bf16_f32 %0, %1, %2" : "=v"(w0) : "v"(p[t * 16 + rb + 0]), "v"(p[t * 16 + rb + 1]));
      asm("v_cvt_pk_bf16_f32 %0, %1, %2" : "=v"(w1) : "v"(p[t * 16 + rb + 2]), "v"(p[t * 16 + rb + 3]));
      ownu[c * 2 + 0] = w0;
      ownu[c * 2 + 1] = w1;
    }

    // ---- Phase 5: V batch B (ks2=2,3) + PV MFMAs ----
    s16x8 vfB[8];
#pragma unroll
    for (int ks2 = 0; ks2 < 2; ++ks2)
#pragma unroll
      for (int dt = 0; dt < 4; ++dt) {
        const int d = dt * 32 + lo;
        const int idx = (d * KVB + (ks2 + 2) * 16 + hi * 8) ^ ((d & 7) << 3);
        vfB[ks2 * 4 + dt] = *(const s16x8*)(&Vb[idx]);
      }

    __builtin_amdgcn_s_setprio(1);
#pragma unroll
    for (int ks2 = 0; ks2 < 4; ++ks2) {
      uint32_t a0 = ownu[4 * ks2 + 0], b0 = ownu[4 * ks2 + 2];
      uint32_t a1 = ownu[4 * ks2 + 1], b1 = ownu[4 * ks2 + 3];
      asm("v_permlane32_swap_b32 %0, %1" : "+v"(a0), "+v"(b0));
      asm("v_permlane32_swap_b32 %0, %1" : "+v"(a1), "+v"(b1));
      union { uint32_t u[4]; s16x8 v; } pu;
      pu.u[0] = a0; pu.u[1] = a1; pu.u[2] = b0; pu.u[3] = b1;
#pragma unroll
      for (int dt = 0; dt < 4; ++dt) {
        s16x8 vf = (ks2 < 2) ? vfA[ks2 * 4 + dt] : vfB[(ks2 - 2) * 4 + dt];
        Oa[dt] = __builtin_amdgcn_mfma_f32_32x32x16_bf16(pu.v, vf, Oa[dt], 0, 0, 0);
      }
    }
    __builtin_amdgcn_s_setprio(0);

    if (kt + 1 < nkt) {
      __syncthreads();  // drains this iter's stage loads (vmcnt(0)) + syncs waves
      cur ^= 1;
    }
  }

  // ---- epilogue: out[q] = O[q]/l ----
  const float linv = 1.0f / l_run;
#pragma unroll
  for (int r = 0; r < 16; ++r) {
    const int src = (r & 3) + 8 * (r >> 2) + 4 * hi;
    const float li = __shfl(linv, src);
    const int qirow = qt * QBLK + wave * 32 + src;
    if (qirow < nq) {
      float* op = out + ((size_t)(qs + qirow) * HH + h) * DD;
      op[0 * 32 + lo] = Oa[0][r] * li;
      op[1 * 32 + lo] = Oa[1][r] * li;
      op[2 * 32 + lo] = Oa[2][r] * li;
      op[3 * 32 + lo] = Oa[3][r] * li;
    }
  }
}

extern "C" void kernel_launch(void* const* d_in, const int* in_sizes, int n_in,
                              void* d_out, int out_size, void* d_ws, size_t ws_size,
                              hipStream_t stream) {
  const float* q = (const float*)d_in[0];
  const float* k = (const float*)d_in[1];
  const float* v = (const float*)d_in[2];
  const int* cuq = (const int*)d_in[3];
  const int* cuk = (const int*)d_in[4];
  float* out = (float*)d_out;
  const int T = in_sizes[0] / (HH * DD);
  const int B = in_sizes[3] - 1;

  unsigned short* kb = (unsigned short*)d_ws;
  unsigned short* vt = kb + (size_t)T * HH * DD;
  const size_t need = (size_t)T * HH * DD * 2 * 2;
  if (ws_size < need) return;

  {
    zero_rows<<<(T + 255) / 256, 256, 0, stream>>>(cuq, out, T, B);
  }
  {
    long total4 = (long)T * HH * DD / 4;
    int blocks = (int)((total4 + 255) / 256);
    kconv<<<blocks, 256, 0, stream>>>(k, kb, T);
  }
  {
    dim3 g((unsigned)((T + 63) / 64), DD / 64, HH);
    vtrans<<<g, 256, 0, stream>>>(v, vt, T);
  }
  {
    const int BH = B * HH;
    const int scap = MAXSEQ < T ? MAXSEQ : T;
    const int qtiles = (scap + QBLK - 1) / QBLK;
    attn_main<<<BH * qtiles, 256, 65536, stream>>>(q, kb, vt, cuq, cuk, out, T, BH);
  }
}